// Round 7
// baseline (112.009 us; speedup 1.0000x reference)
//
#include <hip/hip_runtime.h>

// Problem constants: B=16 batches, A=5 agents, C=512 channels, H=W=16.
#define NB 16
#define NA 5
#define NC 512
#define HW 256
#define NCG 8                    // 64-channel groups
#define NITEMS (NA * NB * NCG)   // 640 blocks

typedef float f4 __attribute__((ext_vector_type(4)));
typedef _Float16 h8 __attribute__((ext_vector_type(8)));   // 16 B = ds b128

static __device__ __forceinline__ h8 splat8(float v) {
    const _Float16 h = (_Float16)v;
    h8 r = {h, h, h, h, h, h, h, h};
    return r;
}

// Block = (batch b, output agent i, 64-channel group). Thread = pixel.
// Key idea: the warp is a channel-independent linear operator. Per pair we
// compute the 16 collapsed-form (tap,weight) ONCE per pixel into registers,
// then sweep 64 channels in 8-channel chunks reusing them: per chunk just
// 16 ds_read_b128 (tap addr VGPR + chunk*4096 imm offset) + pk-fma.
// Slab layout [chunk][px][8ch] -> bank group = tap%8: b128-floor, no pathology.
__global__ __launch_bounds__(256) void fafmimo_amort_kernel(
    const float* __restrict__ feat,   // [A*B][C][256], feat[a*B+b] = local[b][a]
    const float* __restrict__ trans,  // [B][A][A][4][4]
    const int*   __restrict__ numa,   // [B][A], use [:,0]
    float*       __restrict__ out)    // [A*B][C][256]
{
    __shared__ h8 slab[8][HW];        // 32 KiB: [chunk][px], chunk = 8 channels

    const int idx = blockIdx.x;
    const int i   = idx % NA;         // agent fastest: mixes heavy/light blocks
    const int b   = (idx / NA) % NB;
    const int cg  = idx / (NA * NB);
    const int c0  = cg * 64;
    const int px  = threadIdx.x;      // pixel 0..255
    const int x   = px & 15, y = px >> 4;
    const int n   = numa[b * NA];     // block-uniform
    const bool work = (i < n) && (n > 1);

    h8 acc[8];
#pragma unroll
    for (int ch = 0; ch < 8; ++ch) acc[ch] = splat8(0.0f);

    if (work) {
        bool dirty = false;
        for (int jj = 0; jj < 4; ++jj) {
            const int j = jj + (jj >= i);
            if (j < n) {              // block-uniform
                // ---- stage source j's 64-channel slab as fp16 ----
                const float* src = feat + ((size_t)(j * NB + b) * NC + c0) * HW + px;
                if (dirty) __syncthreads();   // prev pair's gathers done
#pragma unroll
                for (int half = 0; half < 2; ++half) {
                    float tmp[32];
#pragma unroll
                    for (int k = 0; k < 32; ++k) tmp[k] = src[(half * 32 + k) * HW];
#pragma unroll
                    for (int cq = 0; cq < 4; ++cq) {
                        h8 v;
#pragma unroll
                        for (int k = 0; k < 8; ++k) v[k] = (_Float16)tmp[cq * 8 + k];
                        slab[half * 4 + cq][px] = v;
                    }
                }
                __syncthreads();
                dirty = true;

                // ---- per-pixel tap table (16 taps of the collapsed 2-stage warp) ----
                const float* tb = trans + (size_t)(((b * NA) + i) * NA + j) * 16;
                const f4 row0 = *(const f4*)tb;        // r00 r01 _ tx
                const f4 row1 = *(const f4*)(tb + 4);  // r10 r11 _ ty
                const float r00 = row0.x, r01 = row0.y;
                const float r10 = row1.x, r11 = row1.y;

                int   ta[16];
                float wa[16];
                {
                    const float dx = 0.25f * row0.w;
                    const float dy = -0.25f * row1.w;
                    const float fdx = floorf(dx), fdy = floorf(dy);
                    const float tx1 = dx - fdx, tx0 = 1.0f - tx1;
                    const float ty1 = dy - fdy, ty0 = 1.0f - ty1;
                    const int ox = x + (int)fdx;
                    const int oy = y + (int)fdy;
                    const float fox = (float)ox - 7.5f;
                    const float foy = (float)oy - 7.5f;
                    const float bxr = r00 * fox + r01 * foy + 7.5f;
                    const float byr = r10 * fox + r11 * foy + 7.5f;
                    int t = 0;
#pragma unroll
                    for (int sy = 0; sy < 2; ++sy)
#pragma unroll
                    for (int sx = 0; sx < 2; ++sx) {
                        const int tox = ox + sx, toy = oy + sy;
                        const bool in2 = (tox >= 0) && (tox < 16) && (toy >= 0) && (toy < 16);
                        const float ws = in2 ? (sx ? tx1 : tx0) * (sy ? ty1 : ty0) : 0.0f;
                        const float cx = bxr + (float)sx * r00 + (float)sy * r01;
                        const float cy = byr + (float)sx * r10 + (float)sy * r11;
                        const float fx0 = floorf(cx), fy0 = floorf(cy);
                        const float wx1 = cx - fx0, wy1 = cy - fy0;
                        const int ix0 = (int)fx0, iy0 = (int)fy0;
                        const float mx0 = (ix0 >= 0 && ix0 < 16) ? 1.0f - wx1 : 0.0f;
                        const float mx1 = (ix0 + 1 >= 0 && ix0 + 1 < 16) ? wx1 : 0.0f;
                        const float my0 = ((iy0 >= 0 && iy0 < 16) ? 1.0f - wy1 : 0.0f) * ws;
                        const float my1 = ((iy0 + 1 >= 0 && iy0 + 1 < 16) ? wy1 : 0.0f) * ws;
                        const int cx0 = min(max(ix0, 0), 15), cx1 = min(max(ix0 + 1, 0), 15);
                        const int cy0 = min(max(iy0, 0), 15), cy1 = min(max(iy0 + 1, 0), 15);
                        ta[t] = cy0 * 16 + cx0; wa[t++] = mx0 * my0;
                        ta[t] = cy0 * 16 + cx1; wa[t++] = mx1 * my0;
                        ta[t] = cy1 * 16 + cx0; wa[t++] = mx0 * my1;
                        ta[t] = cy1 * 16 + cx1; wa[t++] = mx1 * my1;
                    }
                }

                // ---- channel sweep: taps outer, chunks inner ----
                // 8 independent acc chains; addresses reused via imm offsets.
#pragma unroll
                for (int t = 0; t < 16; ++t) {
                    const h8 W = splat8(wa[t]);
                    const h8* sp = &slab[0][ta[t]];
#pragma unroll
                    for (int ch = 0; ch < 8; ++ch)
                        acc[ch] += sp[ch * HW] * W;
                }
            }
        }
    }

    // ---- residual (exact f32) + store ----
    const size_t obase = ((size_t)(i * NB + b) * NC + c0) * HW + px;
    const float* own = feat + obase;
    float* dst = out + obase;
#pragma unroll
    for (int ch = 0; ch < 8; ++ch)
#pragma unroll
        for (int k = 0; k < 8; ++k)
            dst[(ch * 8 + k) * HW] = own[(ch * 8 + k) * HW] + (float)acc[ch][k];
}

extern "C" void kernel_launch(void* const* d_in, const int* in_sizes, int n_in,
                              void* d_out, int out_size, void* d_ws, size_t ws_size,
                              hipStream_t stream) {
    const float* feat  = (const float*)d_in[0];
    const float* trans = (const float*)d_in[1];
    const int*   numa  = (const int*)d_in[2];
    float* out = (float*)d_out;

    fafmimo_amort_kernel<<<dim3(NITEMS), dim3(256), 0, stream>>>(
        feat, trans, numa, out);
}